// Round 10
// baseline (34.446 us; speedup 1.0000x reference)
//
#include <hip/hip_runtime.h>

#define L 8192
#define ATT 1024
#define NPREV 8
#define NB 512   // K2 blocks: 512x512thr, 2 blocks/CU, 16 waves/CU

__device__ inline float fast_tanh(float x) {
    // tanh(x) = 1 - 2/(exp(2x)+1); saturates correctly
    float e = __expf(2.0f * x);
    return 1.0f - 2.0f / (e + 1.0f);
}

// K1: b<1024: bd[b] = dot(dec_z, mlp_dec_w[b,:]) + mlp_dec_b[b] + wvec_b[b]
//     b==1024: zero cacc[1024] + stot (ws is re-poisoned between replays)
__global__ __launch_bounds__(256) void k_prep(
    const float* __restrict__ dec_z, const float* __restrict__ mlp_dec_w,
    const float* __restrict__ mlp_dec_b, const float* __restrict__ wvec_b,
    float* __restrict__ bd, float* __restrict__ cacc, float* __restrict__ stot)
{
    int b = blockIdx.x, t = threadIdx.x;
    if (b < 1024) {
        __shared__ float red[4];
        int wave = t >> 6, lane = t & 63;
        const float4* wrow = (const float4*)(mlp_dec_w + (size_t)b * ATT);
        const float4* dz   = (const float4*)dec_z;
        float4 wv = wrow[t], zv = dz[t];
        float s = wv.x * zv.x + wv.y * zv.y + wv.z * zv.z + wv.w * zv.w;
        #pragma unroll
        for (int off = 32; off; off >>= 1) s += __shfl_down(s, off, 64);
        if (lane == 0) red[wave] = s;
        __syncthreads();
        if (t == 0) bd[b] = red[0] + red[1] + red[2] + red[3]
                            + mlp_dec_b[b] + wvec_b[b];
    } else {
        ((float4*)cacc)[t] = make_float4(0.f, 0.f, 0.f, 0.f);
        if (t == 0) *stot = 0.f;
    }
}

// K2: 512 blocks x 512 thr (8 waves), 16 rows/block, 2 rows/wave.
// Block-local att copy + coverage; score (xor-butterfly, unnormalized exp);
// ctx accumulate; LDS combine; atomicAdd into cacc[1024] and stot.
__global__ __launch_bounds__(512, 4) void k_score_ctx(
    const float* __restrict__ att_prev, const float* __restrict__ pre_enc,
    const float* __restrict__ enc_h, const float* __restrict__ wvec_w,
    const float* __restrict__ bd, const float* __restrict__ gvec_w,
    const float* __restrict__ gvec_b, const float* __restrict__ mask,
    float* __restrict__ out_att,  // [NPREV][L] copies; row 8 = unnormalized u
    float* __restrict__ cacc,     // [1024] atomic ctx accumulator
    float* __restrict__ stot)     // [1] atomic u-sum
{
    __shared__ float lds[4 * 1024];
    __shared__ float cov_s[16];
    __shared__ float uw[8];
    int t = threadIdx.x, b = blockIdx.x;
    int base = b * 16;
    int wave = t >> 6, lane = t & 63;
    float* u_out = out_att + NPREV * L;

    // phase 0: block-local att copy + coverage for these 16 columns
    if (t < 16) {
        float s = 0.f;
        #pragma unroll
        for (int p = 0; p < NPREV; ++p) {
            float v = att_prev[p * L + base + t];
            out_att[p * L + base + t] = v;
            s += v;
        }
        cov_s[t] = s;
    }

    const float4* ww  = (const float4*)wvec_w;
    const float4* bdv = (const float4*)bd;
    const float4* gw  = (const float4*)gvec_w;
    float4 W4[4], BD4[4], G4[4];
    #pragma unroll
    for (int k = 0; k < 4; ++k) {
        W4[k]  = ww[lane + 64 * k];
        BD4[k] = bdv[lane + 64 * k];
        G4[k]  = gw[lane + 64 * k];
    }
    float gb = gvec_b[0];
    __syncthreads();

    const float4* enc = (const float4*)enc_h;
    float4 acc[4] = {};
    float us_w = 0.f;
    #pragma unroll
    for (int rr = 0; rr < 2; ++rr) {
        int r = wave * 2 + rr;
        int l = base + r;
        float cv = cov_s[r];
        const float4* row = (const float4*)(pre_enc + (size_t)l * ATT);
        float4 pe[4], ev[4];
        #pragma unroll
        for (int k = 0; k < 4; ++k) pe[k] = row[lane + 64 * k];
        #pragma unroll
        for (int k = 0; k < 4; ++k) ev[k] = enc[(size_t)l * 256 + 64 * k + lane];
        float s = 0.f;
        #pragma unroll
        for (int k = 0; k < 4; ++k) {
            s += fast_tanh(fmaf(cv, W4[k].x, BD4[k].x) + pe[k].x) * G4[k].x;
            s += fast_tanh(fmaf(cv, W4[k].y, BD4[k].y) + pe[k].y) * G4[k].y;
            s += fast_tanh(fmaf(cv, W4[k].z, BD4[k].z) + pe[k].z) * G4[k].z;
            s += fast_tanh(fmaf(cv, W4[k].w, BD4[k].w) + pe[k].w) * G4[k].w;
        }
        #pragma unroll
        for (int off = 32; off; off >>= 1) s += __shfl_xor(s, off, 64);
        // |2(s+gb+mask)| <= 2*sum|gvec_w| ~ 33 -> exp safe in f32, no max pass
        float uv = __expf(2.0f * (s + gb + mask[l]));
        if (lane == 0) { u_out[l] = uv; us_w += uv; }
        #pragma unroll
        for (int k = 0; k < 4; ++k) {
            acc[k].x += uv * ev[k].x; acc[k].y += uv * ev[k].y;
            acc[k].z += uv * ev[k].z; acc[k].w += uv * ev[k].w;
        }
    }
    if (lane == 0) uw[wave] = us_w;

    // cross-wave combine: waves 4..7 stage, 0..3 add, then 512 thr fold 4 rows
    float4* la = (float4*)lds;
    if (wave >= 4) {
        #pragma unroll
        for (int k = 0; k < 4; ++k)
            la[(wave - 4) * 256 + k * 64 + lane] = acc[k];
    }
    __syncthreads();
    if (wave < 4) {
        #pragma unroll
        for (int k = 0; k < 4; ++k) {
            float4 o = la[wave * 256 + k * 64 + lane];
            o.x += acc[k].x; o.y += acc[k].y;
            o.z += acc[k].z; o.w += acc[k].w;
            la[wave * 256 + k * 64 + lane] = o;
        }
    }
    __syncthreads();
    #pragma unroll
    for (int cc = 0; cc < 2; ++cc) {
        int col = t + cc * 512;
        float v = lds[col] + lds[1024 + col] + lds[2048 + col] + lds[3072 + col];
        atomicAdd(&cacc[col], v);
    }
    if (t == 0) {
        float s = 0.f;
        #pragma unroll
        for (int w = 0; w < 8; ++w) s += uw[w];
        atomicAdd(stot, s);
    }
}

// K3: 33 blocks. b==0: out_c = cacc * inv; b>=1: w *= inv (in place)
__global__ __launch_bounds__(256) void k_finalize(
    const float* __restrict__ stot, const float* __restrict__ cacc,
    float* __restrict__ out_c, float* __restrict__ w_inplace)
{
    int t = threadIdx.x, b = blockIdx.x;
    float inv = 1.0f / *stot;
    if (b == 0) {
        float4 v = ((const float4*)cacc)[t];
        v.x *= inv; v.y *= inv; v.z *= inv; v.w *= inv;
        ((float4*)out_c)[t] = v;
    } else {
        w_inplace[(b - 1) * 256 + t] *= inv;
    }
}

extern "C" void kernel_launch(void* const* d_in, const int* in_sizes, int n_in,
                              void* d_out, int out_size, void* d_ws, size_t ws_size,
                              hipStream_t stream) {
    const float* dec_z     = (const float*)d_in[0];
    const float* att_prev  = (const float*)d_in[1];
    const float* pre_enc   = (const float*)d_in[2];
    const float* enc_h     = (const float*)d_in[3];
    const float* mask      = (const float*)d_in[4];
    const float* wvec_w    = (const float*)d_in[5];
    const float* wvec_b    = (const float*)d_in[6];
    const float* mlp_dec_w = (const float*)d_in[7];
    const float* mlp_dec_b = (const float*)d_in[8];
    const float* gvec_w    = (const float*)d_in[9];
    const float* gvec_b    = (const float*)d_in[10];

    float* out     = (float*)d_out;
    float* out_c   = out;          // [1024]
    float* out_att = out + 1024;   // [9*8192]
    float* out_w   = out_att + 8 * L;

    float* ws   = (float*)d_ws;
    float* bd   = ws;              // 1024
    float* cacc = ws + 1024;       // 1024
    float* stot = ws + 2048;       // 1

    k_prep<<<1025, 256, 0, stream>>>(dec_z, mlp_dec_w, mlp_dec_b, wvec_b,
                                     bd, cacc, stot);
    k_score_ctx<<<NB, 512, 0, stream>>>(att_prev, pre_enc, enc_h, wvec_w, bd,
                                        gvec_w, gvec_b, mask,
                                        out_att, cacc, stot);
    k_finalize<<<33, 256, 0, stream>>>(stot, cacc, out_c, out_w);
}

// Round 11
// 26.366 us; speedup vs baseline: 1.3065x; 1.3065x over previous
//
#include <hip/hip_runtime.h>

#define L 8192
#define ATT 1024
#define NPREV 8
#define NB 256   // K2 blocks (32 rows each)

__device__ inline float fast_tanh(float x) {
    // tanh(x) = 1 - 2/(exp(2x)+1); saturates correctly
    float e = __expf(2.0f * x);
    return 1.0f - 2.0f / (e + 1.0f);
}

// K1: blocks 0..255: wave-per-output matvec (4 outputs/block)
//     blocks 256..287: cov[l] = sum_p att_prev[p][l]; copy old rows to out
__global__ __launch_bounds__(256) void k_prep(
    const float* __restrict__ dec_z, const float* __restrict__ mlp_dec_w,
    const float* __restrict__ mlp_dec_b, const float* __restrict__ wvec_b,
    const float* __restrict__ att_prev,
    float* __restrict__ bd, float* __restrict__ cov, float* __restrict__ out_att)
{
    int b = blockIdx.x, t = threadIdx.x;
    if (b < 256) {
        int wave = t >> 6, lane = t & 63;
        int a = b * 4 + wave;
        const float4* wrow = (const float4*)(mlp_dec_w + (size_t)a * ATT);
        const float4* dz   = (const float4*)dec_z;
        float s = 0.f;
        #pragma unroll
        for (int k = 0; k < 4; ++k) {
            float4 wv = wrow[lane + 64 * k];
            float4 zv = dz[lane + 64 * k];
            s += wv.x * zv.x + wv.y * zv.y + wv.z * zv.z + wv.w * zv.w;
        }
        #pragma unroll
        for (int off = 32; off; off >>= 1) s += __shfl_down(s, off, 64);
        if (lane == 0) bd[a] = s + mlp_dec_b[a] + wvec_b[a];
    } else {
        int l = (b - 256) * 256 + t;
        float s = 0.f;
        #pragma unroll
        for (int p = 0; p < NPREV; ++p) {
            float v = att_prev[p * L + l];
            out_att[p * L + l] = v;
            s += v;
        }
        cov[l] = s;
    }
}

// K2 (R3's verbatim winner): 256 blocks x 1024 thr (16 waves). Wave scores 2
// rows (xor-butterfly, unnormalized exp -> out row 8), accumulates their
// enc_h columns; LDS combine -> partial[b], usum[b].
__global__ __launch_bounds__(1024) void k_score_ctx(
    const float* __restrict__ pre_enc, const float* __restrict__ enc_h,
    const float* __restrict__ cov, const float* __restrict__ wvec_w,
    const float* __restrict__ bd, const float* __restrict__ gvec_w,
    const float* __restrict__ gvec_b, const float* __restrict__ mask,
    float* __restrict__ u_out,    // out_att row 8 (unnormalized)
    float* __restrict__ usum,     // [NB]
    float* __restrict__ partial)  // [NB][ATT]
{
    __shared__ float lds[8 * 1024];
    __shared__ float uw[16];
    int t = threadIdx.x, b = blockIdx.x;
    int base = b * 32;
    int wave = t >> 6, lane = t & 63;

    const float4* ww  = (const float4*)wvec_w;
    const float4* bdv = (const float4*)bd;
    const float4* gw  = (const float4*)gvec_w;
    float4 W4[4], BD4[4], G4[4];
    #pragma unroll
    for (int k = 0; k < 4; ++k) {
        W4[k]  = ww[lane + 64 * k];
        BD4[k] = bdv[lane + 64 * k];
        G4[k]  = gw[lane + 64 * k];
    }
    float gb = gvec_b[0];

    const float4* enc = (const float4*)enc_h;
    float4 acc[4] = {};
    float us_w = 0.f;
    #pragma unroll
    for (int rr = 0; rr < 2; ++rr) {
        int l = base + wave * 2 + rr;
        float cv = cov[l];
        const float4* row = (const float4*)(pre_enc + (size_t)l * ATT);
        float s = 0.f;
        #pragma unroll
        for (int k = 0; k < 4; ++k) {
            float4 pe = row[lane + 64 * k];
            s += fast_tanh(fmaf(cv, W4[k].x, BD4[k].x) + pe.x) * G4[k].x;
            s += fast_tanh(fmaf(cv, W4[k].y, BD4[k].y) + pe.y) * G4[k].y;
            s += fast_tanh(fmaf(cv, W4[k].z, BD4[k].z) + pe.z) * G4[k].z;
            s += fast_tanh(fmaf(cv, W4[k].w, BD4[k].w) + pe.w) * G4[k].w;
        }
        #pragma unroll
        for (int off = 32; off; off >>= 1) s += __shfl_xor(s, off, 64);
        // |2(s+gb+mask)| <= 2*sum|gvec_w| ~ 33 -> exp safe in f32, no max pass
        float uv = __expf(2.0f * (s + gb + mask[l]));
        if (lane == 0) { u_out[l] = uv; us_w += uv; }
        #pragma unroll
        for (int k = 0; k < 4; ++k) {
            float4 v = enc[(size_t)l * 256 + k * 64 + lane];
            acc[k].x += uv * v.x; acc[k].y += uv * v.y;
            acc[k].z += uv * v.z; acc[k].w += uv * v.w;
        }
    }
    if (lane == 0) uw[wave] = us_w;

    // cross-wave combine: waves 8..15 stage, 0..7 add, then 1024 thr fold 8
    float4* la = (float4*)lds;
    if (wave >= 8) {
        #pragma unroll
        for (int k = 0; k < 4; ++k)
            la[(wave - 8) * 256 + k * 64 + lane] = acc[k];
    }
    __syncthreads();
    if (wave < 8) {
        #pragma unroll
        for (int k = 0; k < 4; ++k) {
            float4 o = la[wave * 256 + k * 64 + lane];
            o.x += acc[k].x; o.y += acc[k].y;
            o.z += acc[k].z; o.w += acc[k].w;
            la[wave * 256 + k * 64 + lane] = o;
        }
    }
    __syncthreads();
    {
        float s = 0.f;
        #pragma unroll
        for (int w = 0; w < 8; ++w) s += lds[w * 1024 + t];
        partial[(size_t)b * 1024 + t] = s;
    }
    if (t == 0) {
        float s = 0.f;
        #pragma unroll
        for (int w = 0; w < 16; ++w) s += uw[w];
        usum[b] = s;
    }
}

// K3 (coalesced): 48 blocks. b<16: c columns — wave reads 256B contiguous per
// partial row; b in 16..47: scale w in place.
__global__ __launch_bounds__(256) void k_finalize(
    const float* __restrict__ usum, const float* __restrict__ partial,
    float* __restrict__ out_c, float* __restrict__ w_inplace)
{
    __shared__ float red[4];
    __shared__ float s_inv_sh;
    __shared__ float cred[256];
    int t = threadIdx.x, b = blockIdx.x;
    int wave = t >> 6, lane = t & 63;

    float v = usum[t];
    #pragma unroll
    for (int off = 32; off; off >>= 1) v += __shfl_down(v, off, 64);
    if (lane == 0) red[wave] = v;
    __syncthreads();
    if (t == 0) s_inv_sh = 1.0f / (red[0] + red[1] + red[2] + red[3]);
    __syncthreads();
    float inv = s_inv_sh;

    if (b < 16) {
        int j = b * 64 + (t & 63);
        int r0 = t >> 6;                    // 4 row-groups
        float s = 0.f;
        #pragma unroll 8
        for (int k = 0; k < 64; ++k)
            s += partial[(size_t)(r0 + 4 * k) * 1024 + j];
        cred[t] = s;
        __syncthreads();
        if (t < 128) cred[t] += cred[t + 128];
        __syncthreads();
        if (t < 64) out_c[b * 64 + t] = (cred[t] + cred[t + 64]) * inv;
    } else {
        w_inplace[(b - 16) * 256 + t] *= inv;
    }
}

extern "C" void kernel_launch(void* const* d_in, const int* in_sizes, int n_in,
                              void* d_out, int out_size, void* d_ws, size_t ws_size,
                              hipStream_t stream) {
    const float* dec_z     = (const float*)d_in[0];
    const float* att_prev  = (const float*)d_in[1];
    const float* pre_enc   = (const float*)d_in[2];
    const float* enc_h     = (const float*)d_in[3];
    const float* mask      = (const float*)d_in[4];
    const float* wvec_w    = (const float*)d_in[5];
    const float* wvec_b    = (const float*)d_in[6];
    const float* mlp_dec_w = (const float*)d_in[7];
    const float* mlp_dec_b = (const float*)d_in[8];
    const float* gvec_w    = (const float*)d_in[9];
    const float* gvec_b    = (const float*)d_in[10];

    float* out     = (float*)d_out;
    float* out_c   = out;          // [1024]
    float* out_att = out + 1024;   // [9*8192]
    float* out_w   = out_att + 8 * L;

    float* ws      = (float*)d_ws;
    float* bd      = ws;                        // 1024
    float* cov     = ws + 1024;                 // 8192
    float* usum    = ws + 1024 + 8192;          // 256
    float* partial = ws + 1024 + 8192 + 256;    // NB*1024 (~1 MB)

    k_prep<<<288, 256, 0, stream>>>(dec_z, mlp_dec_w, mlp_dec_b, wvec_b,
                                    att_prev, bd, cov, out_att);
    k_score_ctx<<<NB, 1024, 0, stream>>>(pre_enc, enc_h, cov, wvec_w, bd,
                                         gvec_w, gvec_b, mask,
                                         out_w, usum, partial);
    k_finalize<<<48, 256, 0, stream>>>(usum, partial, out_c, out_w);
}